// Round 2
// baseline (333.369 us; speedup 1.0000x reference)
//
#include <hip/hip_runtime.h>
#include <hip/hip_bf16.h>
#include <stdint.h>

typedef __bf16 bf16_t;
typedef __bf16 bf16x4 __attribute__((ext_vector_type(4)));
typedef __bf16 bf16x8 __attribute__((ext_vector_type(8)));
typedef float f32x4 __attribute__((ext_vector_type(4)));

#define MFMA_16x16x32(A, B, C) __builtin_amdgcn_mfma_f32_16x16x32_bf16(A, B, C, 0, 0, 0)

static constexpr float kScale = 0.08838834764831845f;  // 1/sqrt(128)
static constexpr float kLog2e = 1.4426950408889634f;
static constexpr float kC1 = kScale * kLog2e;  // raw-score -> exp2 argument

// async global->LDS, 16B per lane; LDS dst is wave-uniform base + lane*16
__device__ __forceinline__ void lds_cp16(void* lds, const void* g) {
  __builtin_amdgcn_global_load_lds(
      (__attribute__((address_space(1))) void*)(uintptr_t)g,
      (__attribute__((address_space(3))) void*)(uintptr_t)lds, 16, 0, 0);
}

// Stage a [R rows x K cols] bf16 tile (row-major source, leading dim ldg) into
// chunked LDS layout: elem(r,k) -> chunk(k>>5)*(R*32) + r*32 + (k&31).
template <int R, int K>
__device__ __forceinline__ void stage_tile(bf16_t* lds, const bf16_t* g, int ldg, int tid) {
  constexpr int TOT = R * K;
  constexpr int CH = R * 32;
  constexpr int ITERS = TOT / 2048;  // 256 threads * 8 elems
  const int wave = tid >> 6;
#pragma unroll
  for (int i = 0; i < ITERS; ++i) {
    int linear = i * 2048 + tid * 8;
    int chunk = linear / CH;
    int rem = linear % CH;
    int r = rem >> 5;
    int c = rem & 31;
    lds_cp16(lds + i * 2048 + wave * 512, g + r * ldg + chunk * 32 + c);
  }
}

// Read one MFMA operand fragment from a chunked LDS tile (caller adds kstep*R*32).
__device__ __forceinline__ bf16x8 frag_ld(const bf16_t* lds_chunk, int row, int lane) {
  return *(const bf16x8*)(lds_chunk + row * 32 + ((lane >> 4) << 3));
}

// ---------- elementwise f32 -> bf16 convert ----------
__global__ void cvt_kernel(const float* __restrict__ src, bf16_t* __restrict__ dst) {
  const int i = (blockIdx.x * 256 + threadIdx.x) * 4;
  float4 v = *(const float4*)&src[i];
  bf16x4 o;
  o[0] = (bf16_t)v.x;
  o[1] = (bf16_t)v.y;
  o[2] = (bf16_t)v.z;
  o[3] = (bf16_t)v.w;
  *(bf16x4*)&dst[i] = o;
}

// ---------- tiled transpose f32 src -> bf16 dst: src[mats][R][C] -> dst[mats][C][R] ----------
__global__ void transpose_f32_k(const float* __restrict__ src, bf16_t* __restrict__ dst, int R,
                                int C) {
  __shared__ alignas(16) bf16_t tile[64][72];
  const int t = threadIdx.x;
  const int mat = blockIdx.z;
  const int r0 = blockIdx.x * 64, c0 = blockIdx.y * 64;
  const float* s = src + (size_t)mat * R * C;
  bf16_t* d = dst + (size_t)mat * R * C;
  const int rl = t >> 3, cl = (t & 7) * 8;
#pragma unroll
  for (int half = 0; half < 2; ++half) {
    const int r = r0 + rl + half * 32;
    float4 a = *(const float4*)&s[(size_t)r * C + c0 + cl];
    float4 b = *(const float4*)&s[(size_t)r * C + c0 + cl + 4];
    tile[cl + 0][rl + half * 32] = (bf16_t)a.x;
    tile[cl + 1][rl + half * 32] = (bf16_t)a.y;
    tile[cl + 2][rl + half * 32] = (bf16_t)a.z;
    tile[cl + 3][rl + half * 32] = (bf16_t)a.w;
    tile[cl + 4][rl + half * 32] = (bf16_t)b.x;
    tile[cl + 5][rl + half * 32] = (bf16_t)b.y;
    tile[cl + 6][rl + half * 32] = (bf16_t)b.z;
    tile[cl + 7][rl + half * 32] = (bf16_t)b.w;
  }
  __syncthreads();
  const int cl2 = t >> 3, rl2 = (t & 7) * 8;
  *(bf16x8*)&d[(size_t)(c0 + cl2) * R + r0 + rl2] = *(const bf16x8*)&tile[cl2][rl2];
  *(bf16x8*)&d[(size_t)(c0 + cl2 + 32) * R + r0 + rl2] = *(const bf16x8*)&tile[cl2 + 32][rl2];
}

// ---------- tiled bf16 transpose: src[mats][R][C] -> dst[mats][C][R] ----------
__global__ void transpose_k(const bf16_t* __restrict__ src, bf16_t* __restrict__ dst, int R,
                            int C) {
  __shared__ alignas(16) bf16_t tile[64][72];
  const int t = threadIdx.x;
  const int mat = blockIdx.z;
  const int r0 = blockIdx.x * 64, c0 = blockIdx.y * 64;
  const bf16_t* s = src + (size_t)mat * R * C;
  bf16_t* d = dst + (size_t)mat * R * C;
  const int rl = t >> 3, cl = (t & 7) * 8;
  bf16x8 v0 = *(const bf16x8*)&s[(size_t)(r0 + rl) * C + c0 + cl];
  bf16x8 v1 = *(const bf16x8*)&s[(size_t)(r0 + rl + 32) * C + c0 + cl];
#pragma unroll
  for (int j = 0; j < 8; ++j) {
    tile[cl + j][rl] = v0[j];
    tile[cl + j][rl + 32] = v1[j];
  }
  __syncthreads();
  const int cl2 = t >> 3, rl2 = (t & 7) * 8;
  *(bf16x8*)&d[(size_t)(c0 + cl2) * R + r0 + rl2] = *(const bf16x8*)&tile[cl2][rl2];
  *(bf16x8*)&d[(size_t)(c0 + cl2 + 32) * R + r0 + rl2] = *(const bf16x8*)&tile[cl2 + 32][rl2];
}

// ---------- projections: qkv[mat][4096][128] = Xb @ Wt[mat]^T + bias ----------
// mat = proj*8 + h ; Wt rows are output-cols (e), cols are K (d).
__global__ __launch_bounds__(256, 2) void proj_kernel(const bf16_t* __restrict__ X,
                                                      const bf16_t* __restrict__ Wt,
                                                      const float* __restrict__ bq,
                                                      const float* __restrict__ bk,
                                                      const float* __restrict__ bv,
                                                      bf16_t* __restrict__ qkv) {
  __shared__ alignas(16) bf16_t As[128 * 32];
  __shared__ alignas(16) bf16_t Bs[128 * 32];
  const int t = threadIdx.x, lane = t & 63, w = t >> 6;
  const int l15 = lane & 15, quad = lane >> 4;
  const int ntile = blockIdx.x, mat = blockIdx.y;
  const bf16_t* a0 = X + (size_t)ntile * 128 * 1024;
  const bf16_t* b0 = Wt + (size_t)mat * 131072;
  f32x4 acc[4][4] = {};
  const int rb = (w >> 1) * 64, cb = (w & 1) * 64;
  for (int k0 = 0; k0 < 1024; k0 += 32) {
    stage_tile<128, 32>(As, a0 + k0, 1024, t);
    stage_tile<128, 32>(Bs, b0 + k0, 1024, t);
    __syncthreads();
    bf16x8 af[4], bfr[4];
#pragma unroll
    for (int i = 0; i < 4; ++i) af[i] = frag_ld(As, rb + i * 16 + l15, lane);
#pragma unroll
    for (int j = 0; j < 4; ++j) bfr[j] = frag_ld(Bs, cb + j * 16 + l15, lane);
#pragma unroll
    for (int i = 0; i < 4; ++i)
#pragma unroll
      for (int j = 0; j < 4; ++j) acc[i][j] = MFMA_16x16x32(af[i], bfr[j], acc[i][j]);
    __syncthreads();
  }
  const int proj = mat >> 3, h = mat & 7;
  const float* bias = (proj == 0 ? bq : proj == 1 ? bk : bv) + h * 128;
  bf16_t* outp = qkv + (size_t)mat * (4096 * 128);
#pragma unroll
  for (int i = 0; i < 4; ++i) {
#pragma unroll
    for (int j = 0; j < 4; ++j) {
      const int e = cb + j * 16 + l15;
      const float bval = bias[e];
#pragma unroll
      for (int r = 0; r < 4; ++r) {
        const int n = ntile * 128 + rb + i * 16 + quad * 4 + r;
        outp[(size_t)n * 128 + e] = (bf16_t)(acc[i][j][r] + bval);
      }
    }
  }
}

// ---------- pass A: colsum[h][m] = sum_n exp2(c1 * q[n].k[m]) ----------
__global__ __launch_bounds__(256, 2) void pass_a_kernel(const bf16_t* __restrict__ q,
                                                        const bf16_t* __restrict__ k,
                                                        float* __restrict__ colsum) {
  __shared__ alignas(16) bf16_t kS[64 * 128];  // chunked [4][64][32]
  __shared__ alignas(16) bf16_t qS[64 * 128];
  __shared__ alignas(16) float csred[4][64];
  const int t = threadIdx.x, lane = t & 63, w = t >> 6;
  const int l15 = lane & 15;
  const int mtile = blockIdx.x, h = blockIdx.y;
  const bf16_t* kbase = k + ((size_t)h * 4096 + mtile * 64) * 128;
  const bf16_t* qbase = q + (size_t)h * 4096 * 128;
  stage_tile<64, 128>(kS, kbase, 128, t);
  __syncthreads();
  bf16x8 kf[4][4];  // [msub][kstep], B-operand (col = m)
#pragma unroll
  for (int m = 0; m < 4; ++m)
#pragma unroll
    for (int ks = 0; ks < 4; ++ks) kf[m][ks] = frag_ld(kS + ks * 2048, m * 16 + l15, lane);
  float cs[4] = {0.f, 0.f, 0.f, 0.f};
  for (int ni = 0; ni < 64; ++ni) {
    __syncthreads();
    stage_tile<64, 128>(qS, qbase + (size_t)ni * 64 * 128, 128, t);
    __syncthreads();
    bf16x8 af[4];
#pragma unroll
    for (int ks = 0; ks < 4; ++ks) af[ks] = frag_ld(qS + ks * 2048, w * 16 + l15, lane);
#pragma unroll
    for (int m = 0; m < 4; ++m) {
      f32x4 c = {0.f, 0.f, 0.f, 0.f};
#pragma unroll
      for (int ks = 0; ks < 4; ++ks) c = MFMA_16x16x32(af[ks], kf[m][ks], c);
#pragma unroll
      for (int r = 0; r < 4; ++r) cs[m] += __builtin_exp2f(c[r] * kC1);
    }
  }
#pragma unroll
  for (int m = 0; m < 4; ++m) {
    cs[m] += __shfl_xor(cs[m], 16, 64);
    cs[m] += __shfl_xor(cs[m], 32, 64);
  }
  if (lane < 16) {
#pragma unroll
    for (int m = 0; m < 4; ++m) csred[w][m * 16 + lane] = cs[m];
  }
  __syncthreads();
  if (t < 64)
    colsum[(size_t)h * 4096 + mtile * 64 + t] =
        csred[0][t] + csred[1][t] + csred[2][t] + csred[3][t];
}

__global__ void log2_kernel(const float* __restrict__ cs, float* __restrict__ l2c) {
  const int i = blockIdx.x * 256 + threadIdx.x;
  l2c[i] = __builtin_log2f(cs[i]);
}

// ---------- pass B: z[n][e] = sum_m exp2(c1*s - l2c[m]) * v[m][e]; sigmoid; store f32 ----------
__global__ __launch_bounds__(256, 2) void pass_b_kernel(const bf16_t* __restrict__ q,
                                                        const bf16_t* __restrict__ k,
                                                        const bf16_t* __restrict__ vT,
                                                        const float* __restrict__ l2c,
                                                        float* __restrict__ out) {
  __shared__ alignas(16) bf16_t qS[64 * 128];  // [4][64][32]
  __shared__ alignas(16) bf16_t kS[32 * 128];  // [4][32][32]
  __shared__ alignas(16) bf16_t vS[128 * 32];  // [1][128][32]  (vT rows e, k = m)
  __shared__ alignas(16) float sS[64][36];     // S^T bounce: [n_local][m_local]
  __shared__ alignas(16) float l2S[32];
  const int t = threadIdx.x, lane = t & 63, w = t >> 6;
  const int quad = lane >> 4, l15 = lane & 15;
  const int ntile = blockIdx.x, h = blockIdx.y;
  const bf16_t* qbase = q + ((size_t)h * 4096 + ntile * 64) * 128;
  const bf16_t* kbase = k + (size_t)h * 4096 * 128;
  const bf16_t* vbase = vT + (size_t)h * 128 * 4096;
  const float* lbase = l2c + (size_t)h * 4096;
  stage_tile<64, 128>(qS, qbase, 128, t);
  __syncthreads();
  bf16x8 qf[4];  // B-operand fragments of q (col = this wave's n), loop-invariant
#pragma unroll
  for (int ks = 0; ks < 4; ++ks) qf[ks] = frag_ld(qS + ks * 2048, w * 16 + l15, lane);
  f32x4 zacc[8] = {};
  for (int mi = 0; mi < 128; ++mi) {
    const int m0 = mi * 32;
    __syncthreads();  // previous iteration's LDS reads done before restage
    stage_tile<32, 128>(kS, kbase + (size_t)m0 * 128, 128, t);
    stage_tile<128, 32>(vS, vbase + m0, 4096, t);
    if (t < 8) lds_cp16(l2S, lbase + m0 + t * 4);
    __syncthreads();
    // S^T[m][n] for this wave's 16 n-columns; C-frag regs are consecutive m -> b128 write
#pragma unroll
    for (int ms = 0; ms < 2; ++ms) {
      f32x4 c = {0.f, 0.f, 0.f, 0.f};
#pragma unroll
      for (int ks = 0; ks < 4; ++ks) {
        bf16x8 kfg = frag_ld(kS + ks * 1024, ms * 16 + l15, lane);
        c = MFMA_16x16x32(kfg, qf[ks], c);
      }
      *(f32x4*)&sS[w * 16 + l15][ms * 16 + quad * 4] = c;
    }
    // read back this lane's PV A-fragment: P[n=w*16+l15][m=quad*8+j]  (same-wave data only)
    f32x4 s0 = *(const f32x4*)&sS[w * 16 + l15][quad * 8];
    f32x4 s1 = *(const f32x4*)&sS[w * 16 + l15][quad * 8 + 4];
    f32x4 g0 = *(const f32x4*)&l2S[quad * 8];
    f32x4 g1 = *(const f32x4*)&l2S[quad * 8 + 4];
    bf16x8 p;
#pragma unroll
    for (int j = 0; j < 4; ++j) p[j] = (bf16_t)__builtin_exp2f(s0[j] * kC1 - g0[j]);
#pragma unroll
    for (int j = 0; j < 4; ++j) p[4 + j] = (bf16_t)__builtin_exp2f(s1[j] * kC1 - g1[j]);
#pragma unroll
    for (int es = 0; es < 8; ++es) {
      bf16x8 vf = frag_ld(vS, es * 16 + l15, lane);
      zacc[es] = MFMA_16x16x32(p, vf, zacc[es]);
    }
  }
  // epilogue: sigmoid + store f32  out[n][h*128+e]
#pragma unroll
  for (int es = 0; es < 8; ++es) {
    const int e = es * 16 + l15;
#pragma unroll
    for (int r = 0; r < 4; ++r) {
      const int n = ntile * 64 + w * 16 + quad * 4 + r;
      const float x = zacc[es][r];
      out[(size_t)n * 1024 + h * 128 + e] = 1.f / (1.f + __builtin_exp2f(-x * kLog2e));
    }
  }
}

extern "C" void kernel_launch(void* const* d_in, const int* in_sizes, int n_in, void* d_out,
                              int out_size, void* d_ws, size_t ws_size, hipStream_t stream) {
  (void)in_sizes;
  (void)n_in;
  (void)out_size;
  (void)ws_size;
  const float* X = (const float*)d_in[0];
  const float* Wq = (const float*)d_in[1];
  const float* bq = (const float*)d_in[2];
  const float* Wk = (const float*)d_in[3];
  const float* bk = (const float*)d_in[4];
  const float* Wv = (const float*)d_in[5];
  const float* bv = (const float*)d_in[6];
  float* out = (float*)d_out;
  char* ws = (char*)d_ws;
  // region A (0 .. 8,388,608): Xb during proj, then vTp for pass_b (lifetimes disjoint)
  bf16_t* Xb = (bf16_t*)(ws);
  bf16_t* vTp = (bf16_t*)(ws);
  // region B (8,388,608 .. 14,680,064): Wt during proj, then csum/l2c (lifetimes disjoint)
  bf16_t* Wt = (bf16_t*)(ws + 8388608);
  float* csum = (float*)(ws + 8388608);
  float* l2c = (float*)(ws + 8388608 + 131072);
  // region C (14,680,064 .. 39,845,888): qkv
  bf16_t* qkv = (bf16_t*)(ws + 14680064);
  bf16_t* qp = qkv;
  bf16_t* kp = qkv + (size_t)8 * 4096 * 128;
  bf16_t* vp = qkv + (size_t)16 * 4096 * 128;

  cvt_kernel<<<4096, 256, 0, stream>>>(X, Xb);
  transpose_f32_k<<<dim3(16, 2, 8), 256, 0, stream>>>(Wq, Wt + (size_t)0 * 8 * 131072, 1024, 128);
  transpose_f32_k<<<dim3(16, 2, 8), 256, 0, stream>>>(Wk, Wt + (size_t)1 * 8 * 131072, 1024, 128);
  transpose_f32_k<<<dim3(16, 2, 8), 256, 0, stream>>>(Wv, Wt + (size_t)2 * 8 * 131072, 1024, 128);
  proj_kernel<<<dim3(32, 24), 256, 0, stream>>>(Xb, Wt, bq, bk, bv, qkv);
  transpose_k<<<dim3(64, 2, 8), 256, 0, stream>>>(vp, vTp, 4096, 128);
  pass_a_kernel<<<dim3(64, 8), 256, 0, stream>>>(qp, kp, csum);
  log2_kernel<<<128, 256, 0, stream>>>(csum, l2c);
  pass_b_kernel<<<dim3(64, 8), 256, 0, stream>>>(qp, kp, vTp, l2c, out);
}

// Round 3
// 309.521 us; speedup vs baseline: 1.0771x; 1.0771x over previous
//
#include <hip/hip_runtime.h>
#include <hip/hip_bf16.h>
#include <stdint.h>

typedef __bf16 bf16_t;
typedef __bf16 bf16x4 __attribute__((ext_vector_type(4)));
typedef __bf16 bf16x8 __attribute__((ext_vector_type(8)));
typedef float f32x4 __attribute__((ext_vector_type(4)));

#define MFMA_16x16x32(A, B, C) __builtin_amdgcn_mfma_f32_16x16x32_bf16(A, B, C, 0, 0, 0)

static constexpr float kScale = 0.08838834764831845f;  // 1/sqrt(128)
static constexpr float kLog2e = 1.4426950408889634f;
static constexpr float kC1 = kScale * kLog2e;  // raw-score -> exp2 argument

// async global->LDS, 16B per lane; LDS dst is wave-uniform base + lane*16
__device__ __forceinline__ void lds_cp16(void* lds, const void* g) {
  __builtin_amdgcn_global_load_lds(
      (__attribute__((address_space(1))) void*)(uintptr_t)g,
      (__attribute__((address_space(3))) void*)(uintptr_t)lds, 16, 0, 0);
}

// Stage a [R rows x K cols] bf16 tile (row-major source, leading dim ldg) into
// chunked LDS layout: elem(r,k) -> chunk(k>>5)*(R*32) + r*32 + (k&31).
template <int R, int K>
__device__ __forceinline__ void stage_tile(bf16_t* lds, const bf16_t* g, int ldg, int tid) {
  constexpr int TOT = R * K;
  constexpr int CH = R * 32;
  constexpr int ITERS = TOT / 2048;  // 256 threads * 8 elems
  const int wave = tid >> 6;
#pragma unroll
  for (int i = 0; i < ITERS; ++i) {
    int linear = i * 2048 + tid * 8;
    int chunk = linear / CH;
    int rem = linear % CH;
    int r = rem >> 5;
    int c = rem & 31;
    lds_cp16(lds + i * 2048 + wave * 512, g + r * ldg + chunk * 32 + c);
  }
}

// Read one MFMA operand fragment from a chunked LDS tile (caller adds kstep*R*32).
__device__ __forceinline__ bf16x8 frag_ld(const bf16_t* lds_chunk, int row, int lane) {
  return *(const bf16x8*)(lds_chunk + row * 32 + ((lane >> 4) << 3));
}

// ---------- zero out accumulator buffers (out 4M f32 + csum 32K f32) ----------
__global__ void zero_kernel(float* __restrict__ out, float* __restrict__ csum) {
  const int b = blockIdx.x;
  if (b < 4096) {
    const int i = b * 1024 + threadIdx.x * 4;
    *(f32x4*)&out[i] = f32x4{0.f, 0.f, 0.f, 0.f};
  } else {
    const int i = (b - 4096) * 1024 + threadIdx.x * 4;
    *(f32x4*)&csum[i] = f32x4{0.f, 0.f, 0.f, 0.f};
  }
}

// ---------- elementwise f32 -> bf16 convert ----------
__global__ void cvt_kernel(const float* __restrict__ src, bf16_t* __restrict__ dst) {
  const int i = (blockIdx.x * 256 + threadIdx.x) * 4;
  float4 v = *(const float4*)&src[i];
  bf16x4 o;
  o[0] = (bf16_t)v.x;
  o[1] = (bf16_t)v.y;
  o[2] = (bf16_t)v.z;
  o[3] = (bf16_t)v.w;
  *(bf16x4*)&dst[i] = o;
}

// ---------- tiled transpose f32 src -> bf16 dst: src[mats][R][C] -> dst[mats][C][R] ----------
__global__ void transpose_f32_k(const float* __restrict__ src, bf16_t* __restrict__ dst, int R,
                                int C) {
  __shared__ alignas(16) bf16_t tile[64][72];
  const int t = threadIdx.x;
  const int mat = blockIdx.z;
  const int r0 = blockIdx.x * 64, c0 = blockIdx.y * 64;
  const float* s = src + (size_t)mat * R * C;
  bf16_t* d = dst + (size_t)mat * R * C;
  const int rl = t >> 3, cl = (t & 7) * 8;
#pragma unroll
  for (int half = 0; half < 2; ++half) {
    const int r = r0 + rl + half * 32;
    float4 a = *(const float4*)&s[(size_t)r * C + c0 + cl];
    float4 b = *(const float4*)&s[(size_t)r * C + c0 + cl + 4];
    tile[cl + 0][rl + half * 32] = (bf16_t)a.x;
    tile[cl + 1][rl + half * 32] = (bf16_t)a.y;
    tile[cl + 2][rl + half * 32] = (bf16_t)a.z;
    tile[cl + 3][rl + half * 32] = (bf16_t)a.w;
    tile[cl + 4][rl + half * 32] = (bf16_t)b.x;
    tile[cl + 5][rl + half * 32] = (bf16_t)b.y;
    tile[cl + 6][rl + half * 32] = (bf16_t)b.z;
    tile[cl + 7][rl + half * 32] = (bf16_t)b.w;
  }
  __syncthreads();
  const int cl2 = t >> 3, rl2 = (t & 7) * 8;
  *(bf16x8*)&d[(size_t)(c0 + cl2) * R + r0 + rl2] = *(const bf16x8*)&tile[cl2][rl2];
  *(bf16x8*)&d[(size_t)(c0 + cl2 + 32) * R + r0 + rl2] = *(const bf16x8*)&tile[cl2 + 32][rl2];
}

// ---------- tiled bf16 transpose: src[mats][R][C] -> dst[mats][C][R] ----------
__global__ void transpose_k(const bf16_t* __restrict__ src, bf16_t* __restrict__ dst, int R,
                            int C) {
  __shared__ alignas(16) bf16_t tile[64][72];
  const int t = threadIdx.x;
  const int mat = blockIdx.z;
  const int r0 = blockIdx.x * 64, c0 = blockIdx.y * 64;
  const bf16_t* s = src + (size_t)mat * R * C;
  bf16_t* d = dst + (size_t)mat * R * C;
  const int rl = t >> 3, cl = (t & 7) * 8;
  bf16x8 v0 = *(const bf16x8*)&s[(size_t)(r0 + rl) * C + c0 + cl];
  bf16x8 v1 = *(const bf16x8*)&s[(size_t)(r0 + rl + 32) * C + c0 + cl];
#pragma unroll
  for (int j = 0; j < 8; ++j) {
    tile[cl + j][rl] = v0[j];
    tile[cl + j][rl + 32] = v1[j];
  }
  __syncthreads();
  const int cl2 = t >> 3, rl2 = (t & 7) * 8;
  *(bf16x8*)&d[(size_t)(c0 + cl2) * R + r0 + rl2] = *(const bf16x8*)&tile[cl2][rl2];
  *(bf16x8*)&d[(size_t)(c0 + cl2 + 32) * R + r0 + rl2] = *(const bf16x8*)&tile[cl2 + 32][rl2];
}

// ---------- projections ----------
// q mats 0..7 -> base+0..8MB ; k mats 8..15 -> 8..16MB ; v mats 16..23 -> 24..32MB (hole for Xb)
__global__ __launch_bounds__(256, 2) void proj_kernel(const bf16_t* __restrict__ X,
                                                      const bf16_t* __restrict__ Wt,
                                                      const float* __restrict__ bq,
                                                      const float* __restrict__ bk,
                                                      const float* __restrict__ bv,
                                                      bf16_t* __restrict__ qkv) {
  __shared__ alignas(16) bf16_t As[128 * 32];
  __shared__ alignas(16) bf16_t Bs[128 * 32];
  const int t = threadIdx.x, lane = t & 63, w = t >> 6;
  const int l15 = lane & 15, quad = lane >> 4;
  const int ntile = blockIdx.x, mat = blockIdx.y;
  const bf16_t* a0 = X + (size_t)ntile * 128 * 1024;
  const bf16_t* b0 = Wt + (size_t)mat * 131072;
  f32x4 acc[4][4] = {};
  const int rb = (w >> 1) * 64, cb = (w & 1) * 64;
  for (int k0 = 0; k0 < 1024; k0 += 32) {
    stage_tile<128, 32>(As, a0 + k0, 1024, t);
    stage_tile<128, 32>(Bs, b0 + k0, 1024, t);
    __syncthreads();
    bf16x8 af[4], bfr[4];
#pragma unroll
    for (int i = 0; i < 4; ++i) af[i] = frag_ld(As, rb + i * 16 + l15, lane);
#pragma unroll
    for (int j = 0; j < 4; ++j) bfr[j] = frag_ld(Bs, cb + j * 16 + l15, lane);
#pragma unroll
    for (int i = 0; i < 4; ++i)
#pragma unroll
      for (int j = 0; j < 4; ++j) acc[i][j] = MFMA_16x16x32(af[i], bfr[j], acc[i][j]);
    __syncthreads();
  }
  const int proj = mat >> 3, h = mat & 7;
  const float* bias = (proj == 0 ? bq : proj == 1 ? bk : bv) + h * 128;
  const size_t moff = (size_t)mat * 524288 + (mat >= 16 ? 4194304 : 0);
  bf16_t* outp = qkv + moff;
#pragma unroll
  for (int i = 0; i < 4; ++i) {
#pragma unroll
    for (int j = 0; j < 4; ++j) {
      const int e = cb + j * 16 + l15;
      const float bval = bias[e];
#pragma unroll
      for (int r = 0; r < 4; ++r) {
        const int n = ntile * 128 + rb + i * 16 + quad * 4 + r;
        outp[(size_t)n * 128 + e] = (bf16_t)(acc[i][j][r] + bval);
      }
    }
  }
}

// ---------- pass A: csum[h][m] += sum_{n in half} exp2(c1 * q[n].k[m]) ----------
// grid (64 mtiles of 64m, 8 h, 2 n-half). k fragments hoisted (64 VGPR).
__global__ __launch_bounds__(256, 4) void pass_a_kernel(const bf16_t* __restrict__ q,
                                                        const bf16_t* __restrict__ k,
                                                        float* __restrict__ csum) {
  __shared__ alignas(16) bf16_t kS[64 * 128];  // chunked [4][64][32]
  __shared__ alignas(16) bf16_t qS[64 * 128];
  __shared__ alignas(16) float csred[4][64];
  const int t = threadIdx.x, lane = t & 63, w = t >> 6;
  const int l15 = lane & 15;
  const int mtile = blockIdx.x, h = blockIdx.y, nc = blockIdx.z;
  const bf16_t* kbase = k + ((size_t)h * 4096 + mtile * 64) * 128;
  const bf16_t* qbase = q + ((size_t)h * 4096 + nc * 2048) * 128;
  stage_tile<64, 128>(kS, kbase, 128, t);
  __syncthreads();
  bf16x8 kf[4][4];  // [msub][kstep], B-operand (col = m)
#pragma unroll
  for (int m = 0; m < 4; ++m)
#pragma unroll
    for (int ks = 0; ks < 4; ++ks) kf[m][ks] = frag_ld(kS + ks * 2048, m * 16 + l15, lane);
  float cs[4] = {0.f, 0.f, 0.f, 0.f};
  for (int rnd = 0; rnd < 32; ++rnd) {
    __syncthreads();
    stage_tile<64, 128>(qS, qbase + (size_t)rnd * 64 * 128, 128, t);
    __syncthreads();
    bf16x8 af[4];
#pragma unroll
    for (int ks = 0; ks < 4; ++ks) af[ks] = frag_ld(qS + ks * 2048, w * 16 + l15, lane);
#pragma unroll
    for (int m = 0; m < 4; ++m) {
      f32x4 c = {0.f, 0.f, 0.f, 0.f};
#pragma unroll
      for (int ks = 0; ks < 4; ++ks) c = MFMA_16x16x32(af[ks], kf[m][ks], c);
#pragma unroll
      for (int r = 0; r < 4; ++r) cs[m] += __builtin_exp2f(c[r] * kC1);
    }
  }
#pragma unroll
  for (int m = 0; m < 4; ++m) {
    cs[m] += __shfl_xor(cs[m], 16, 64);
    cs[m] += __shfl_xor(cs[m], 32, 64);
  }
  if (lane < 16) {
#pragma unroll
    for (int m = 0; m < 4; ++m) csred[w][m * 16 + lane] = cs[m];
  }
  __syncthreads();
  if (t < 64)
    unsafeAtomicAdd(&csum[(size_t)h * 4096 + mtile * 64 + t],
                    csred[0][t] + csred[1][t] + csred[2][t] + csred[3][t]);
}

__global__ void log2_kernel(float* __restrict__ cs) {
  const int i = blockIdx.x * 256 + threadIdx.x;
  cs[i] = __builtin_log2f(cs[i]);
}

// ---------- pass B ----------
// grid (64 ntiles of 64n, 8 h, 2 m-chunk). Waves: (w&1)=n-half(32n), (w>>1)=m-parity(32m).
// Each wave: 32n x 128e accum; per round stages 64m; bf16-P LDS bounce; pair-reduce;
// unsafeAtomicAdd f32 into d_out (acts as accumulator), sigmoid applied by a later kernel.
__global__ __launch_bounds__(256, 3) void pass_b_kernel(const bf16_t* __restrict__ q,
                                                        const bf16_t* __restrict__ k,
                                                        const bf16_t* __restrict__ vT,
                                                        const float* __restrict__ l2c,
                                                        float* __restrict__ out) {
  __shared__ alignas(16) bf16_t kS[64 * 128];   // chunked [4][64m][32k]   16KB
  __shared__ alignas(16) bf16_t vS[128 * 64];   // chunked [2][128e][32m]  16KB
  __shared__ alignas(16) char qsS[16384];       // qS (64n x 128k) then sS (P bounce)
  __shared__ alignas(16) float l2S[64];
  bf16_t* qS = (bf16_t*)qsS;
  const int t = threadIdx.x, lane = t & 63, w = t >> 6;
  const int quad = lane >> 4, l15 = lane & 15;
  const int npar = w & 1, mpar = w >> 1;
  const int ntile = blockIdx.x, h = blockIdx.y, mc = blockIdx.z;
  const bf16_t* qbase = q + ((size_t)h * 4096 + ntile * 64) * 128;
  const bf16_t* kb = k + ((size_t)h * 4096 + mc * 2048) * 128;
  const bf16_t* vb = vT + (size_t)h * 128 * 4096 + mc * 2048;
  const float* lb = l2c + (size_t)h * 4096 + mc * 2048;
  stage_tile<64, 128>(qS, qbase, 128, t);
  __syncthreads();
  bf16x8 qf[2][4];  // B-operand q fragments (col = n), loop-invariant
#pragma unroll
  for (int nsub = 0; nsub < 2; ++nsub)
#pragma unroll
    for (int ks = 0; ks < 4; ++ks)
      qf[nsub][ks] = frag_ld(qS + ks * 2048, npar * 32 + nsub * 16 + l15, lane);
  bf16_t* sW = (bf16_t*)qsS + w * 1280;  // per-wave P bounce: [32n][40] bf16
  f32x4 zacc[2][8] = {};
  for (int rnd = 0; rnd < 32; ++rnd) {
    const int m0 = rnd * 64;
    __syncthreads();  // prior round's reads (and qf loads) done before restage
    stage_tile<64, 128>(kS, kb + (size_t)m0 * 128, 128, t);
    stage_tile<128, 64>(vS, vb + m0, 4096, t);
    if (t < 16) lds_cp16(l2S, lb + m0 + t * 4);
    __syncthreads();
    // S^T: rows m (wave's 32m tile), cols n (wave's 32n)
    f32x4 cc[2][2];  // [ms][nsub]
#pragma unroll
    for (int ms = 0; ms < 2; ++ms)
#pragma unroll
      for (int nsub = 0; nsub < 2; ++nsub) cc[ms][nsub] = f32x4{0.f, 0.f, 0.f, 0.f};
#pragma unroll
    for (int ks = 0; ks < 4; ++ks) {
      bf16x8 kfg0 = frag_ld(kS + ks * 2048, mpar * 32 + l15, lane);
      bf16x8 kfg1 = frag_ld(kS + ks * 2048, mpar * 32 + 16 + l15, lane);
#pragma unroll
      for (int nsub = 0; nsub < 2; ++nsub) {
        cc[0][nsub] = MFMA_16x16x32(kfg0, qf[nsub][ks], cc[0][nsub]);
        cc[1][nsub] = MFMA_16x16x32(kfg1, qf[nsub][ks], cc[1][nsub]);
      }
    }
    // exp2 in C-layout (row m = quad*4+r, col n = l15), bf16 pack, bounce through sW
#pragma unroll
    for (int ms = 0; ms < 2; ++ms) {
      float g0 = l2S[mpar * 32 + ms * 16 + quad * 4 + 0];
      float g1 = l2S[mpar * 32 + ms * 16 + quad * 4 + 1];
      float g2 = l2S[mpar * 32 + ms * 16 + quad * 4 + 2];
      float g3 = l2S[mpar * 32 + ms * 16 + quad * 4 + 3];
#pragma unroll
      for (int nsub = 0; nsub < 2; ++nsub) {
        bf16x4 pv;
        pv[0] = (bf16_t)__builtin_exp2f(cc[ms][nsub][0] * kC1 - g0);
        pv[1] = (bf16_t)__builtin_exp2f(cc[ms][nsub][1] * kC1 - g1);
        pv[2] = (bf16_t)__builtin_exp2f(cc[ms][nsub][2] * kC1 - g2);
        pv[3] = (bf16_t)__builtin_exp2f(cc[ms][nsub][3] * kC1 - g3);
        *(bf16x4*)&sW[(nsub * 16 + l15) * 40 + ms * 16 + quad * 4] = pv;
      }
    }
    // read back P A-fragments (same-wave data; compiler inserts lgkmcnt wait)
    bf16x8 pf[2];
#pragma unroll
    for (int nsub = 0; nsub < 2; ++nsub)
      pf[nsub] = *(const bf16x8*)&sW[(nsub * 16 + l15) * 40 + quad * 8];
    // PV: z[n][e] += P * V  (K=32 = wave's m tile)
#pragma unroll
    for (int es = 0; es < 8; ++es) {
      bf16x8 vf = frag_ld(vS + mpar * 4096, es * 16 + l15, lane);
#pragma unroll
      for (int nsub = 0; nsub < 2; ++nsub)
        zacc[nsub][es] = MFMA_16x16x32(pf[nsub], vf, zacc[nsub][es]);
    }
  }
  // in-block m-parity pair reduce: waves 2,3 dump; waves 0,1 merge + atomicAdd to out
  __syncthreads();
  if (mpar == 1) {
    float* dst = (w == 2) ? (float*)kS : (float*)vS;
#pragma unroll
    for (int i = 0; i < 16; ++i) *(f32x4*)&dst[i * 256 + lane * 4] = zacc[i >> 3][i & 7];
  }
  __syncthreads();
  if (mpar == 0) {
    const float* src = (w == 0) ? (const float*)kS : (const float*)vS;
#pragma unroll
    for (int nsub = 0; nsub < 2; ++nsub) {
#pragma unroll
      for (int es = 0; es < 8; ++es) {
        f32x4 o = *(const f32x4*)&src[(nsub * 8 + es) * 256 + lane * 4];
        const int e = es * 16 + l15;
#pragma unroll
        for (int r = 0; r < 4; ++r) {
          const int n = ntile * 64 + npar * 32 + nsub * 16 + quad * 4 + r;
          unsafeAtomicAdd(&out[(size_t)n * 1024 + h * 128 + e], zacc[nsub][es][r] + o[r]);
        }
      }
    }
  }
}

// ---------- sigmoid in place on out ----------
__global__ void sigmoid_kernel(float* __restrict__ out) {
  const int i = blockIdx.x * 1024 + threadIdx.x * 4;
  f32x4 v = *(const f32x4*)&out[i];
#pragma unroll
  for (int j = 0; j < 4; ++j) v[j] = 1.f / (1.f + __builtin_exp2f(-v[j] * kLog2e));
  *(f32x4*)&out[i] = v;
}

extern "C" void kernel_launch(void* const* d_in, const int* in_sizes, int n_in, void* d_out,
                              int out_size, void* d_ws, size_t ws_size, hipStream_t stream) {
  (void)in_sizes;
  (void)n_in;
  (void)out_size;
  (void)ws_size;
  const float* X = (const float*)d_in[0];
  const float* Wq = (const float*)d_in[1];
  const float* bq = (const float*)d_in[2];
  const float* Wk = (const float*)d_in[3];
  const float* bk = (const float*)d_in[4];
  const float* Wv = (const float*)d_in[5];
  const float* bv = (const float*)d_in[6];
  float* out = (float*)d_out;
  char* ws = (char*)d_ws;
  // layout (bytes):
  //  0        - 8388608 : q
  //  8388608  - 16777216: k
  //  16777216 - 25165824: Xb (cvt out, proj in) -> vTp (after proj)
  //  25165824 - 33554432: v (proj out; dead after v-transpose)
  //  33554432 - 39845888: Wt (dead after proj)
  //  39845888 - 39976960: csum -> l2c (in-place log2)
  bf16_t* qp = (bf16_t*)(ws);
  bf16_t* kp = (bf16_t*)(ws + 8388608);
  bf16_t* Xb = (bf16_t*)(ws + 16777216);
  bf16_t* vTp = (bf16_t*)(ws + 16777216);
  bf16_t* vp = (bf16_t*)(ws + 25165824);
  bf16_t* Wt = (bf16_t*)(ws + 33554432);
  float* csum = (float*)(ws + 39845888);

  zero_kernel<<<4128, 256, 0, stream>>>(out, csum);
  cvt_kernel<<<4096, 256, 0, stream>>>(X, Xb);
  transpose_f32_k<<<dim3(16, 2, 8), 256, 0, stream>>>(Wq, Wt + (size_t)0 * 8 * 131072, 1024, 128);
  transpose_f32_k<<<dim3(16, 2, 8), 256, 0, stream>>>(Wk, Wt + (size_t)1 * 8 * 131072, 1024, 128);
  transpose_f32_k<<<dim3(16, 2, 8), 256, 0, stream>>>(Wv, Wt + (size_t)2 * 8 * 131072, 1024, 128);
  proj_kernel<<<dim3(32, 24), 256, 0, stream>>>(Xb, Wt, bq, bk, bv, qp);
  transpose_k<<<dim3(64, 2, 8), 256, 0, stream>>>(vp, vTp, 4096, 128);
  pass_a_kernel<<<dim3(64, 8, 2), 256, 0, stream>>>(qp, kp, csum);
  log2_kernel<<<128, 256, 0, stream>>>(csum);
  pass_b_kernel<<<dim3(64, 8, 2), 256, 0, stream>>>(qp, kp, vTp, csum, out);
  sigmoid_kernel<<<4096, 256, 0, stream>>>(out);
}